// Round 8
// baseline (817.310 us; speedup 1.0000x reference)
//
#include <hip/hip_runtime.h>

#define DIN 64
#define DOUT 64
#define MAXK 32
#define QG 64           // queries per coarse bucket
#define CHUNK 3072      // max edges per LDS sort pass in phaseBd

typedef __bf16 bf16x8 __attribute__((ext_vector_type(8)));
typedef float  f32x4  __attribute__((ext_vector_type(4)));

static __device__ inline unsigned short f2b(float x) {
    return __builtin_bit_cast(unsigned short, (__bf16)x);
}

// ---------------- pre: coarse hist || W->bf16 frags || ref->bf16 ----------------
// Roles by blockIdx; hist first (on the critical path to scan/scatter).
// bucket = q >> 6 (QG=64, NB = M/64 <= 1024 bins). Block-aggregated global
// atomics only (per-edge global atomics FORBIDDEN: r13 = 156us disaster).

__global__ __launch_bounds__(256) void pre2_kernel(
    const float* __restrict__ W, unsigned short* __restrict__ Wt, int wtot,
    const float* __restrict__ ref, unsigned short* __restrict__ refb, int rtot8,
    const int* __restrict__ eq, int E, int* __restrict__ qcount,
    int HB, int CWB)
{
    const int t = threadIdx.x;
    if ((int)blockIdx.x < HB) {
        __shared__ int l[1024];
        #pragma unroll
        for (int s4 = 0; s4 < 4; ++s4) l[t + s4 * 256] = 0;
        __syncthreads();
        const int stride = HB * 256;
        for (int i = (int)blockIdx.x * 256 + t; i < E; i += stride)
            atomicAdd(&l[((unsigned)eq[i]) >> 6], 1);
        __syncthreads();
        #pragma unroll
        for (int s4 = 0; s4 < 4; ++s4) {
            int v = l[t + s4 * 256];
            if (v) atomicAdd(&qcount[t + s4 * 256], v);
        }
    } else if ((int)blockIdx.x < HB + CWB) {
        // W[k][d1][d2] fp32 -> frag-major bf16 Wt[k][t][h][lane][j]
        int i = ((int)blockIdx.x - HB) * 256 + t;
        if (i < wtot) {
            int j    = i & 7;
            int lane = (i >> 3) & 63;
            int h    = (i >> 9) & 1;
            int tt   = (i >> 10) & 3;
            int k    = i >> 12;
            int col  = lane & 15;
            int quad = lane >> 4;
            int d1 = h * 32 + quad * 8 + j;
            int d2 = tt * 16 + col;
            Wt[i] = f2b(W[(k * 64 + d1) * 64 + d2]);
        }
    } else {
        // ref fp32 -> bf16 (row-major [N][64]), 8 elems/thread
        int i8 = ((int)blockIdx.x - HB - CWB) * 256 + t;
        if (i8 < rtot8) {
            const float* rp = ref + (size_t)i8 * 8;
            f32x4 r0 = *reinterpret_cast<const f32x4*>(rp);
            f32x4 r1 = *reinterpret_cast<const f32x4*>(rp + 4);
            bf16x8 o;
            #pragma unroll
            for (int j = 0; j < 4; ++j) {
                o[j]     = (__bf16)r0[j];
                o[4 + j] = (__bf16)r1[j];
            }
            *reinterpret_cast<bf16x8*>(refb + (size_t)i8 * 8) = o;
        }
    }
}

// ---------------- coarse scan (single block, 1024 thr) ----------------
__global__ void p1_scan_kernel(const int* __restrict__ qcount,
                               int* __restrict__ gbase, int* __restrict__ gcursor,
                               int NB) {
    __shared__ int sh[1024];
    int t = threadIdx.x;
    int v = (t < NB) ? qcount[t] : 0;
    sh[t] = v;
    __syncthreads();
    #pragma unroll
    for (int o = 1; o < 1024; o <<= 1) {
        int x = (t >= o) ? sh[t - o] : 0;
        __syncthreads();
        sh[t] += x;
        __syncthreads();
    }
    int ex = sh[t] - v;
    if (t < NB) { gbase[t] = ex; gcursor[t] = ex; }
}

// ---------------- coarse scatter (block-aggregated; r7-proven shape) ----------------
// Payload 8B: {r | k<<16 | (q&63)<<21, w_bits}  (needs N<=65536, K0<=32)

__global__ __launch_bounds__(1024) void scat_kernel(
    const int* __restrict__ eq, const int* __restrict__ er,
    const int* __restrict__ ek, const float* __restrict__ ew,
    int E, int* __restrict__ gcursor, uint2* __restrict__ tmp)
{
    __shared__ int bin[1024];
    __shared__ int base[1024];
    const int t = threadIdx.x;
    bin[t] = 0;
    __syncthreads();
    const int i0 = (int)blockIdx.x * 8192;
    unsigned key[8];
    unsigned rank[8];
    uint2 pay[8];
    #pragma unroll
    for (int u = 0; u < 8; ++u) {
        int i = i0 + u * 1024 + t;
        if (i < E) {
            int q = eq[i];
            unsigned b = ((unsigned)q) >> 6;
            key[u] = b;
            rank[u] = atomicAdd(&bin[b], 1);
            pay[u] = make_uint2((unsigned)er[i] | ((unsigned)ek[i] << 16) |
                                ((unsigned)(q & (QG - 1)) << 21),
                                __float_as_uint(ew[i]));
        } else {
            key[u] = 0xFFFFFFFFu;
        }
    }
    __syncthreads();
    int c = bin[t];
    if (c) base[t] = atomicAdd(&gcursor[t], c);
    __syncthreads();
    #pragma unroll
    for (int u = 0; u < 8; ++u) {
        if (key[u] != 0xFFFFFFFFu)
            tmp[(size_t)base[key[u]] + rank[u]] = pay[u];
    }
}

// ---------------- Phase Bd: direct per-edge MFMA compute (round 18) ----------------
// Replaces phaseA + p2 + phaseB: T (226MB write + 201MB HBM fetch) deleted.
// Per bucket (64 queries): stage+fine-sort the bucket's edges by k in LDS,
// then per 16-edge same-k batch: gather 16 refb rows (L2/L3-resident, 8.4MB
// total), 8x mfma_16x16x32_bf16 against Wt[k] (L2-resident), scale rows by
// w_e, accumulate into LDS acc[64][64] via ds_add_f32 (2-way banks = free).
// Fragment/epilogue math copied verbatim from the proven phaseA body.
// k-straddle batches handled by ballot loop over distinct k (w=0 masking;
// ~1.3 iters/batch at avg k-run ~57). Edges beyond CHUNK processed in
// additional chunk passes (acc persists).

__global__ __launch_bounds__(512) void phaseBd_kernel(
    const unsigned short* __restrict__ refb,   // [N][64] bf16
    const unsigned short* __restrict__ Wt,     // [K0][4096] frag-major bf16
    const uint2* __restrict__ tmp,
    const int* __restrict__ gbase, const int* __restrict__ qcount,
    float* __restrict__ out)
{
    __shared__ uint2 srt[CHUNK];               // 24KB
    __shared__ float acc[QG * 64];             // 16KB
    __shared__ float msg[8][16 * 66];          // 33KB (66-stride kills bank conflicts)
    __shared__ int khist[32], kbase[32];

    const int t    = threadIdx.x;
    const int lane = t & 63;
    const int wid  = t >> 6;                   // 8 waves
    const int col  = lane & 15;
    const int quad = lane >> 4;
    const int b    = blockIdx.x;
    const int s    = gbase[b];
    const int L    = qcount[b];

    for (int i = t; i < QG * 64; i += 512) acc[i] = 0.f;

    for (int c0 = 0; c0 < L; c0 += CHUNK) {
        const int Lc = (L - c0 < CHUNK) ? (L - c0) : CHUNK;
        if (t < 32) khist[t] = 0;
        __syncthreads();
        for (int i = t; i < Lc; i += 512)
            atomicAdd(&khist[(tmp[s + c0 + i].x >> 16) & 31], 1);
        __syncthreads();
        if (t == 0) {
            int a = 0;
            #pragma unroll
            for (int j = 0; j < 32; ++j) { int v = khist[j]; kbase[j] = a; khist[j] = a; a += v; }
        }
        __syncthreads();
        for (int i = t; i < Lc; i += 512) {
            uint2 p = tmp[s + c0 + i];
            int k = (int)((p.x >> 16) & 31u);
            int pos = atomicAdd(&khist[k], 1);
            srt[pos] = p;
        }
        __syncthreads();

        const int nbat = (Lc + 15) >> 4;
        float* mw = &msg[wid][0];
        for (int bat = wid; bat < nbat; bat += 8) {
            const int e0 = bat << 4;
            const int ei = e0 + col;
            const bool valid = (ei < Lc);
            uint2 mv = valid ? srt[ei] : make_uint2(0u, 0u);
            const unsigned r  = mv.x & 0xFFFFu;
            const int      kv = (int)((mv.x >> 16) & 31u);
            const int      qv = (int)((mv.x >> 21) & (unsigned)(QG - 1));
            const float    w  = __uint_as_float(mv.y);

            // gather refb row r (b-frag layout identical to proven phaseA)
            const unsigned short* rp = refb + (size_t)r * 64;
            bf16x8 b0 = *reinterpret_cast<const bf16x8*>(rp + quad * 8);
            bf16x8 b1 = *reinterpret_cast<const bf16x8*>(rp + 32 + quad * 8);

            bool done = !valid;
            while (true) {
                unsigned long long mask = __ballot(!done);
                if (mask == 0ull) break;
                int first = (int)__builtin_ctzll(mask);
                int kc = __shfl(kv, first);
                bool act = (!done) && (kv == kc);
                float wm = act ? w : 0.f;
                const unsigned short* Wk = Wt + (size_t)kc * 4096;
                #pragma unroll
                for (int tt = 0; tt < 4; ++tt) {
                    const unsigned short* ap = Wk + (size_t)tt * 1024 + lane * 8;
                    bf16x8 a0 = *reinterpret_cast<const bf16x8*>(ap);
                    bf16x8 a1 = *reinterpret_cast<const bf16x8*>(ap + 512);
                    f32x4 c = {0.f, 0.f, 0.f, 0.f};
                    c = __builtin_amdgcn_mfma_f32_16x16x32_bf16(a0, b0, c, 0, 0, 0);
                    c = __builtin_amdgcn_mfma_f32_16x16x32_bf16(a1, b1, c, 0, 0, 0);
                    const int mb = col * 66 + tt * 16 + quad * 4;
                    mw[mb + 0] = c[0] * wm;
                    mw[mb + 1] = c[1] * wm;
                    mw[mb + 2] = c[2] * wm;
                    mw[mb + 3] = c[3] * wm;
                }
                #pragma unroll
                for (int row = 0; row < 16; ++row) {
                    int qr = __shfl(qv, row);
                    atomicAdd(&acc[qr * 64 + lane], mw[row * 66 + lane]);
                }
                done = done || act;
            }
        }
        __syncthreads();
    }

    const size_t ob = (size_t)b * (QG * 64);
    for (int i = t; i < QG * 64; i += 512)
        out[ob + i] = acc[i];
}

// ================= fallback path (round-1): kernel-bucketed fp32 =================

__global__ void hist_kernel(const int* __restrict__ ek, int E, int* __restrict__ counts) {
    __shared__ int l[MAXK];
    if (threadIdx.x < MAXK) l[threadIdx.x] = 0;
    __syncthreads();
    int stride = gridDim.x * blockDim.x;
    for (int i = blockIdx.x * blockDim.x + threadIdx.x; i < E; i += stride)
        atomicAdd(&l[ek[i]], 1);
    __syncthreads();
    if (threadIdx.x < MAXK) {
        int v = l[threadIdx.x];
        if (v) atomicAdd(&counts[threadIdx.x], v);
    }
}

__global__ void scan_kernel(const int* __restrict__ counts, int K,
                            int* __restrict__ start, int* __restrict__ cursor) {
    if (threadIdx.x == 0 && blockIdx.x == 0) {
        int acc = 0;
        for (int k = 0; k < K; ++k) {
            start[k] = acc;
            cursor[k] = acc;
            acc += counts[k];
        }
    }
}

__global__ void scatter_kernel(const int* __restrict__ ek, int E,
                               int* __restrict__ cursor, int* __restrict__ sorted) {
    __shared__ int lcnt[MAXK], lbase[MAXK], lpos[MAXK];
    if (threadIdx.x < MAXK) { lcnt[threadIdx.x] = 0; lpos[threadIdx.x] = 0; }
    __syncthreads();
    int i = blockIdx.x * blockDim.x + threadIdx.x;
    int k = 0;
    bool valid = (i < E);
    if (valid) { k = ek[i]; atomicAdd(&lcnt[k], 1); }
    __syncthreads();
    if (threadIdx.x < MAXK) {
        int v = lcnt[threadIdx.x];
        if (v) lbase[threadIdx.x] = atomicAdd(&cursor[threadIdx.x], v);
    }
    __syncthreads();
    if (valid) {
        int slot = lbase[k] + atomicAdd(&lpos[k], 1);
        sorted[slot] = i;
    }
}

__global__ __launch_bounds__(256) void mp_bucket_kernel(
    const float* __restrict__ W, const float* __restrict__ ref,
    const int* __restrict__ e_ref, const int* __restrict__ e_query,
    const float* __restrict__ e_weight, const int* __restrict__ sorted,
    const int* __restrict__ start, const int* __restrict__ counts,
    float* __restrict__ out)
{
    const int k = blockIdx.y;
    const int lane = threadIdx.x & 63;
    const int wid = threadIdx.x >> 6;

    float wreg[DIN];
    const float* Wk = W + k * DIN * DOUT;
    #pragma unroll
    for (int d = 0; d < DIN; ++d) wreg[d] = Wk[d * DOUT + lane];

    const int s = start[k];
    const int c = counts[k];
    const int nwaves = gridDim.x * 4;

    for (int i = blockIdx.x * 4 + wid; i < c; i += nwaves) {
        int eid = __builtin_amdgcn_readfirstlane(sorted[s + i]);
        int r = e_ref[eid];
        int q = e_query[eid];
        float w = e_weight[eid];
        const float* row = ref + r * DIN;
        float a0 = 0.f, a1 = 0.f, a2 = 0.f, a3 = 0.f;
        #pragma unroll
        for (int d = 0; d < DIN; d += 4) {
            a0 += row[d + 0] * wreg[d + 0];
            a1 += row[d + 1] * wreg[d + 1];
            a2 += row[d + 2] * wreg[d + 2];
            a3 += row[d + 3] * wreg[d + 3];
        }
        atomicAdd(&out[q * DOUT + lane], ((a0 + a1) + (a2 + a3)) * w);
    }
}

// =================================================================================

extern "C" void kernel_launch(void* const* d_in, const int* in_sizes, int n_in,
                              void* d_out, int out_size, void* d_ws, size_t ws_size,
                              hipStream_t stream) {
    const float* W        = (const float*)d_in[0];   // [K0, 64, 64]
    const float* ref      = (const float*)d_in[1];   // [N, 64]
    const int*   e_kernel = (const int*)d_in[2];     // [E]
    const int*   e_ref    = (const int*)d_in[3];     // [E]
    const int*   e_query  = (const int*)d_in[4];     // [E]
    const float* e_weight = (const float*)d_in[6];   // [E]

    const int K0 = in_sizes[0] / (DIN * DOUT);
    const int N  = in_sizes[1] / DIN;
    const int E  = in_sizes[2];
    const int M  = out_size / DOUT;
    const int NB = M / QG;           // coarse buckets (64 queries each)

    float* out = (float*)d_out;

    // ---- plan A workspace carve ----
    size_t off = 0;
    auto alloc = [&](size_t bytes, size_t align) {
        off = (off + align - 1) / align * align;
        size_t r = off; off += bytes; return r;
    };
    size_t o_tmp     = alloc((size_t)E * 8, 16);
    size_t o_qcount  = alloc(1024 * 4, 4);
    size_t o_gbase   = alloc(1024 * 4, 4);
    size_t o_gcursor = alloc(1024 * 4, 4);
    size_t o_wt      = alloc((size_t)K0 * 4096 * 2, 16);
    size_t o_refb    = alloc((size_t)N * 64 * 2, 16);
    size_t needA = off;

    bool planA_ok = (ws_size >= needA) && (M % QG == 0) && (NB >= 1) && (NB <= 1024) &&
                    (N <= 65536) && (K0 <= 32) && ((N * 64) % 8 == 0);

    if (planA_ok) {
        char* ws = (char*)d_ws;
        uint2* tmp           = (uint2*)(ws + o_tmp);
        int*  qcount         = (int*)(ws + o_qcount);
        int*  gbase          = (int*)(ws + o_gbase);
        int*  gcursor        = (int*)(ws + o_gcursor);
        unsigned short* Wt   = (unsigned short*)(ws + o_wt);
        unsigned short* refb = (unsigned short*)(ws + o_refb);

        const int HB   = 512;                            // hist blocks
        const int CWB  = (K0 * 4096 + 255) / 256;        // W-convert blocks
        const int RT8  = (N * 64) / 8;                   // ref bf16-convert items
        const int RB   = (RT8 + 255) / 256;              // ref-convert blocks
        const int SCB  = (E + 8191) / 8192;              // scatter blocks

        hipMemsetAsync(qcount, 0, 1024 * sizeof(int), stream);

        pre2_kernel<<<HB + CWB + RB, 256, 0, stream>>>(
            W, Wt, K0 * 4096, ref, refb, RT8, e_query, E, qcount, HB, CWB);

        p1_scan_kernel<<<1, 1024, 0, stream>>>(qcount, gbase, gcursor, NB);

        scat_kernel<<<SCB, 1024, 0, stream>>>(e_query, e_ref, e_kernel, e_weight,
                                              E, gcursor, tmp);

        phaseBd_kernel<<<NB, 512, 0, stream>>>(refb, Wt, tmp, gbase, qcount, out);
    } else {
        hipMemsetAsync(out, 0, (size_t)out_size * sizeof(float), stream);
        size_t needB = (size_t)(96 + E) * sizeof(int);
        if (ws_size >= needB) {
            int* ws_i   = (int*)d_ws;
            int* counts = ws_i;
            int* start  = ws_i + 32;
            int* cursor = ws_i + 64;
            int* sorted = ws_i + 96;
            hipMemsetAsync(counts, 0, 96 * sizeof(int), stream);
            hist_kernel<<<512, 256, 0, stream>>>(e_kernel, E, counts);
            scan_kernel<<<1, 64, 0, stream>>>(counts, K0, start, cursor);
            scatter_kernel<<<(E + 255) / 256, 256, 0, stream>>>(e_kernel, E, cursor, sorted);
            dim3 grid(64, K0);
            mp_bucket_kernel<<<grid, 256, 0, stream>>>(W, ref, e_ref, e_query, e_weight,
                                                       sorted, start, counts, out);
        }
    }
}

// Round 9
// 299.188 us; speedup vs baseline: 2.7318x; 2.7318x over previous
//
#include <hip/hip_runtime.h>

#define DIN 64
#define DOUT 64
#define MAXK 32
#define QG 128           // queries per coarse bucket -> NB = M/128 <= 512 bins
#define KCH 4            // k's per fused phaseA slice

typedef __bf16 bf16x8 __attribute__((ext_vector_type(8)));
typedef float  f32x4  __attribute__((ext_vector_type(4)));
typedef unsigned int u32x4 __attribute__((ext_vector_type(4)));

static __device__ inline unsigned short f2b(float x) {
    return __builtin_bit_cast(unsigned short, (__bf16)x);
}
static __device__ inline float b2f(unsigned short u) {
    return __uint_as_float(((unsigned int)u) << 16);
}

// ---------------- pre: coarse hist (q>>7, 512 bins) || W->bf16 frags ----------------
// qcount zeroed by the preceding hipMemsetAsync. Block-aggregated global
// atomics only (per-edge global ATOMICS forbidden: r13 = 156us; plain
// idempotent byte STORES are fine and used for the map in scat below).

__global__ __launch_bounds__(256) void pre_kernel(
    const float* __restrict__ W, unsigned short* __restrict__ Wt, int total,
    const int* __restrict__ eq, int E, int* __restrict__ qcount, int HB)
{
    const int t = threadIdx.x;
    if ((int)blockIdx.x < HB) {
        __shared__ int l[512];
        l[t] = 0; l[t + 256] = 0;
        __syncthreads();
        const int stride = HB * 256;
        for (int i = (int)blockIdx.x * 256 + t; i < E; i += stride)
            atomicAdd(&l[((unsigned)eq[i]) >> 7], 1);
        __syncthreads();
        int v0 = l[t];       if (v0) atomicAdd(&qcount[t], v0);
        int v1 = l[t + 256]; if (v1) atomicAdd(&qcount[t + 256], v1);
    } else {
        int i = ((int)blockIdx.x - HB) * 256 + t;
        if (i < total) {
            int j    = i & 7;
            int lane = (i >> 3) & 63;
            int h    = (i >> 9) & 1;
            int tt   = (i >> 10) & 3;
            int k    = i >> 12;
            int col  = lane & 15;
            int quad = lane >> 4;
            int d1 = h * 32 + quad * 8 + j;
            int d2 = tt * 16 + col;
            Wt[i] = f2b(W[(k * 64 + d1) * 64 + d2]);
        }
    }
}

// ---------------- Phase A body, 16-wave blocks (r7-proven, 3.5+ TB/s fused) ----------------
// T layout [k][N][d2]; LDS-transpose epilogue -> coalesced 16B CACHED stores
// (nt = 1.5x write amp, r9). MAPPED variant skips rows never referenced by
// any edge (~41%): map built by scat_kernel in the PREVIOUS dispatch.

template <bool MAPPED>
static __device__ __forceinline__ void phaseA_body16(
    const float* __restrict__ ref,
    const unsigned short* __restrict__ Wt,
    const unsigned char* __restrict__ map,
    unsigned short* __restrict__ T,
    int Nn, int nblk, int k0, int k1, char* lds)
{
    const int t    = threadIdx.x;
    const int lane = t & 63;
    const int wid  = t >> 6;                 // 16 waves
    const int col  = lane & 15;
    const int quad = lane >> 4;
    const int n0   = nblk * 256 + wid * 16;
    const int row  = n0 + col;
    char* buf = lds + wid * 2304;

    const float* rp = ref + (size_t)row * 64;
    f32x4 r0 = *reinterpret_cast<const f32x4*>(rp + quad * 8);
    f32x4 r1 = *reinterpret_cast<const f32x4*>(rp + quad * 8 + 4);
    f32x4 r2 = *reinterpret_cast<const f32x4*>(rp + 32 + quad * 8);
    f32x4 r3 = *reinterpret_cast<const f32x4*>(rp + 32 + quad * 8 + 4);
    bf16x8 b0, b1;
    #pragma unroll
    for (int i = 0; i < 4; ++i) {
        b0[i]     = (__bf16)r0[i];
        b0[4 + i] = (__bf16)r1[i];
        b1[i]     = (__bf16)r2[i];
        b1[4 + i] = (__bf16)r3[i];
    }

    const int rrow = lane >> 2;
    const int rq   = lane & 3;

    for (int k = k0; k < k1; ++k) {
        unsigned char use = 1;
        if (MAPPED) use = map[(size_t)k * Nn + n0 + rrow];
        const unsigned short* Wk = Wt + (size_t)k * 4096;
        #pragma unroll
        for (int tt = 0; tt < 4; ++tt) {
            const unsigned short* ap = Wk + (size_t)tt * 1024 + lane * 8;
            bf16x8 a0 = *reinterpret_cast<const bf16x8*>(ap);
            bf16x8 a1 = *reinterpret_cast<const bf16x8*>(ap + 512);
            f32x4 c = {0.f, 0.f, 0.f, 0.f};
            c = __builtin_amdgcn_mfma_f32_16x16x32_bf16(a0, b0, c, 0, 0, 0);
            c = __builtin_amdgcn_mfma_f32_16x16x32_bf16(a1, b1, c, 0, 0, 0);
            unsigned int lo = (unsigned int)f2b(c[0]) | ((unsigned int)f2b(c[1]) << 16);
            unsigned int hi = (unsigned int)f2b(c[2]) | ((unsigned int)f2b(c[3]) << 16);
            *reinterpret_cast<uint2*>(buf + col * 144 + tt * 32 + quad * 8) =
                make_uint2(lo, hi);
        }
        u32x4 v0 = *reinterpret_cast<const u32x4*>(buf + rrow * 144 + rq * 32);
        u32x4 v1 = *reinterpret_cast<const u32x4*>(buf + rrow * 144 + rq * 32 + 16);
        if (use) {
            size_t gb = ((size_t)k * Nn + n0 + rrow) * 64 + rq * 16;
            *reinterpret_cast<u32x4*>(T + gb)     = v0;
            *reinterpret_cast<u32x4*>(T + gb + 8) = v1;
        }
    }
}

// ---------------- fused: coarse scatter (+inline scan, +map build) || phaseA k<K1 ----------------
// Scan dispatch deleted: every scatter block recomputes the 512-bin exclusive
// scan from qcount in LDS; gcursor pre-zeroed so slot = local_ex + global rank.
// Block 0 publishes gbase + qstart[M]=E for the next dispatches.
// Payload 8B: {r | k<<16 | (q&127)<<21, w_bits}  (N<=65536, K0<=32)

__global__ __launch_bounds__(1024) void fused_scat_kernel(
    const float* __restrict__ ref, const unsigned short* __restrict__ Wt,
    unsigned short* __restrict__ T, int K0, int Nn, int SCB, int NA2, int K1,
    const int* __restrict__ eq, const int* __restrict__ er,
    const int* __restrict__ ek, const float* __restrict__ ew,
    int E, const int* __restrict__ qcount, int* __restrict__ gbase,
    int* __restrict__ gcursor, int* __restrict__ qstart, int M,
    uint2* __restrict__ tmp, unsigned char* __restrict__ map)
{
    __shared__ __align__(16) char ldsbuf[16 * 2304];
    __shared__ int sh[512];
    __shared__ int bin[512];
    __shared__ int base[512];
    const int t = threadIdx.x;

    if ((int)blockIdx.x < SCB) {
        // inline 512-bin exclusive scan of qcount
        int v = 0;
        if (t < 512) { v = qcount[t]; sh[t] = v; }
        __syncthreads();
        #pragma unroll
        for (int o = 1; o < 512; o <<= 1) {
            int x = (t >= o && t < 512) ? sh[t - o] : 0;
            __syncthreads();
            if (t < 512) sh[t] += x;
            __syncthreads();
        }
        if (t < 512) sh[t] -= v;                  // exclusive
        if ((int)blockIdx.x == 0 && t < 512) gbase[t] = sh[t];
        if ((int)blockIdx.x == 0 && t == 0) qstart[M] = E;
        if (t < 512) bin[t] = 0;
        __syncthreads();

        const int i0 = (int)blockIdx.x * 8192;
        unsigned key[8];
        unsigned rank[8];
        uint2 pay[8];
        #pragma unroll
        for (int u = 0; u < 8; ++u) {
            int i = i0 + u * 1024 + t;
            if (i < E) {
                int q  = eq[i];
                int rr = er[i];
                int kk = ek[i];
                unsigned b = ((unsigned)q) >> 7;
                key[u] = b;
                rank[u] = atomicAdd(&bin[b], 1);
                pay[u] = make_uint2((unsigned)rr | ((unsigned)kk << 16) |
                                    ((unsigned)(q & (QG - 1)) << 21),
                                    __float_as_uint(ew[i]));
                map[(size_t)kk * Nn + rr] = 1;    // idempotent byte store (no atomic)
            } else {
                key[u] = 0xFFFFFFFFu;
            }
        }
        __syncthreads();
        if (t < 512) {
            int c = bin[t];
            if (c) base[t] = sh[t] + atomicAdd(&gcursor[t], c);
        }
        __syncthreads();
        #pragma unroll
        for (int u = 0; u < 8; ++u) {
            if (key[u] != 0xFFFFFFFFu)
                tmp[(size_t)base[key[u]] + rank[u]] = pay[u];
        }
    } else {
        const int ab   = (int)blockIdx.x - SCB;
        const int nblk = ab % NA2;
        const int sl   = ab / NA2;
        const int k0   = sl * KCH;
        if (k0 >= K1) return;
        int k1 = k0 + KCH;
        if (k1 > K1) k1 = K1;
        phaseA_body16<false>(ref, Wt, nullptr, T, Nn, nblk, k0, k1, ldsbuf);
    }
}

// ---------------- fused: fine sort (p2) || phaseA k>=K1 (map-predicated) ----------------

__global__ __launch_bounds__(1024) void fused_p2_kernel(
    const float* __restrict__ ref, const unsigned short* __restrict__ Wt,
    const unsigned char* __restrict__ map, unsigned short* __restrict__ T,
    int K0, int Nn, int NB, int NA2, int K1,
    const uint2* __restrict__ tmp, const int* __restrict__ gbase,
    const int* __restrict__ qcount, uint2* __restrict__ rec,
    int* __restrict__ qstart)
{
    __shared__ __align__(16) char ldsbuf[16 * 2304];
    __shared__ int fine[QG];
    __shared__ int foff[QG];
    __shared__ int vsave[QG];
    const int t = threadIdx.x;

    if ((int)blockIdx.x < NB) {
        const int b = (int)blockIdx.x;
        const int s = gbase[b];
        const int L = qcount[b];
        if (t < QG) fine[t] = 0;
        __syncthreads();
        for (int i = t; i < L; i += 1024)
            atomicAdd(&fine[(tmp[s + i].x >> 21) & (QG - 1)], 1);
        __syncthreads();
        if (t < QG) vsave[t] = fine[t];
        __syncthreads();
        #pragma unroll
        for (int o = 1; o < QG; o <<= 1) {
            int x = (t >= o && t < QG) ? fine[t - o] : 0;
            __syncthreads();
            if (t < QG) fine[t] += x;
            __syncthreads();
        }
        if (t < QG) {
            int ex = fine[t] - vsave[t];
            foff[t] = ex;
            qstart[b * QG + t] = s + ex;
            fine[t] = 0;
        }
        __syncthreads();
        for (int i = t; i < L; i += 1024) {
            uint2 p = tmp[s + i];
            unsigned fb = (p.x >> 21) & (QG - 1);
            int r = atomicAdd(&fine[fb], 1);
            rec[(size_t)s + foff[fb] + r] = p;
        }
    } else {
        const int ab   = (int)blockIdx.x - NB;
        const int nblk = ab % NA2;
        const int sl   = ab / NA2;
        const int k0   = K1 + sl * KCH;
        if (k0 >= K0) return;
        int k1 = k0 + KCH;
        if (k1 > K0) k1 = K0;
        phaseA_body16<true>(ref, Wt, map, T, Nn, nblk, k0, k1, ldsbuf);
    }
}

// ---------------- Phase B: per-query gather-accumulate (PROVEN; never restructure) ----------------
// 65-72us @ 3.4 TB/s, 201MB compulsory random fetch. Lives on massive TLP
// (65K waves, 8-deep ILP): bucket-resident variants died (r6: 517us, r8:
// 706us). No nontemporal loads, no deeper buffering (r10).

__global__ __launch_bounds__(256) void phaseB_kernel(
    const unsigned short* __restrict__ T,    // [K0][N][64] bf16
    const uint2* __restrict__ rec,
    const int* __restrict__ qstart,
    float* __restrict__ out, int Nn)
{
    const int lane = threadIdx.x & 63;
    const int wid  = threadIdx.x >> 6;
    const int q    = blockIdx.x * 4 + wid;

    int beg = qstart[q];
    int end = qstart[q + 1];
    int cnt = end - beg;
    float acc = 0.f;

    if (cnt <= 64) {
        uint2 rv = make_uint2(0u, 0u);
        if (lane < cnt) rv = rec[beg + lane];
        int j = 0;
        for (; j + 8 <= cnt; j += 8) {
            float partial[8];
            #pragma unroll
            for (int u = 0; u < 8; ++u) {
                unsigned mx = (unsigned)__builtin_amdgcn_readlane((int)rv.x, j + u);
                unsigned mw = (unsigned)__builtin_amdgcn_readlane((int)rv.y, j + u);
                unsigned off = (((mx >> 16) & 31) * (unsigned)Nn + (mx & 0xFFFFu)) * 64u
                               + (unsigned)lane;
                partial[u] = __uint_as_float(mw) * b2f(T[off]);
            }
            #pragma unroll
            for (int u = 0; u < 8; ++u) acc += partial[u];
        }
        for (; j < cnt; ++j) {
            unsigned mx = (unsigned)__builtin_amdgcn_readlane((int)rv.x, j);
            unsigned mw = (unsigned)__builtin_amdgcn_readlane((int)rv.y, j);
            unsigned off = (((mx >> 16) & 31) * (unsigned)Nn + (mx & 0xFFFFu)) * 64u
                           + (unsigned)lane;
            acc = fmaf(__uint_as_float(mw), b2f(T[off]), acc);
        }
    } else {
        for (int j = beg; j < end; ++j) {
            uint2 v0 = rec[j];
            unsigned m0 = __builtin_amdgcn_readfirstlane(v0.x);
            float w0 = __uint_as_float(__builtin_amdgcn_readfirstlane(v0.y));
            unsigned off = (((m0 >> 16) & 31) * (unsigned)Nn + (m0 & 0xFFFFu)) * 64u
                           + (unsigned)lane;
            acc = fmaf(w0, b2f(T[off]), acc);
        }
    }
    out[(size_t)q * 64 + lane] = acc;
}

// ================= fallback path (round-1): kernel-bucketed fp32 =================

__global__ void hist_kernel(const int* __restrict__ ek, int E, int* __restrict__ counts) {
    __shared__ int l[MAXK];
    if (threadIdx.x < MAXK) l[threadIdx.x] = 0;
    __syncthreads();
    int stride = gridDim.x * blockDim.x;
    for (int i = blockIdx.x * blockDim.x + threadIdx.x; i < E; i += stride)
        atomicAdd(&l[ek[i]], 1);
    __syncthreads();
    if (threadIdx.x < MAXK) {
        int v = l[threadIdx.x];
        if (v) atomicAdd(&counts[threadIdx.x], v);
    }
}

__global__ void scan_kernel(const int* __restrict__ counts, int K,
                            int* __restrict__ start, int* __restrict__ cursor) {
    if (threadIdx.x == 0 && blockIdx.x == 0) {
        int acc = 0;
        for (int k = 0; k < K; ++k) {
            start[k] = acc;
            cursor[k] = acc;
            acc += counts[k];
        }
    }
}

__global__ void scatter_kernel(const int* __restrict__ ek, int E,
                               int* __restrict__ cursor, int* __restrict__ sorted) {
    __shared__ int lcnt[MAXK], lbase[MAXK], lpos[MAXK];
    if (threadIdx.x < MAXK) { lcnt[threadIdx.x] = 0; lpos[threadIdx.x] = 0; }
    __syncthreads();
    int i = blockIdx.x * blockDim.x + threadIdx.x;
    int k = 0;
    bool valid = (i < E);
    if (valid) { k = ek[i]; atomicAdd(&lcnt[k], 1); }
    __syncthreads();
    if (threadIdx.x < MAXK) {
        int v = lcnt[threadIdx.x];
        if (v) lbase[threadIdx.x] = atomicAdd(&cursor[threadIdx.x], v);
    }
    __syncthreads();
    if (valid) {
        int slot = lbase[k] + atomicAdd(&lpos[k], 1);
        sorted[slot] = i;
    }
}

__global__ __launch_bounds__(256) void mp_bucket_kernel(
    const float* __restrict__ W, const float* __restrict__ ref,
    const int* __restrict__ e_ref, const int* __restrict__ e_query,
    const float* __restrict__ e_weight, const int* __restrict__ sorted,
    const int* __restrict__ start, const int* __restrict__ counts,
    float* __restrict__ out)
{
    const int k = blockIdx.y;
    const int lane = threadIdx.x & 63;
    const int wid = threadIdx.x >> 6;

    float wreg[DIN];
    const float* Wk = W + k * DIN * DOUT;
    #pragma unroll
    for (int d = 0; d < DIN; ++d) wreg[d] = Wk[d * DOUT + lane];

    const int s = start[k];
    const int c = counts[k];
    const int nwaves = gridDim.x * 4;

    for (int i = blockIdx.x * 4 + wid; i < c; i += nwaves) {
        int eid = __builtin_amdgcn_readfirstlane(sorted[s + i]);
        int r = e_ref[eid];
        int q = e_query[eid];
        float w = e_weight[eid];
        const float* row = ref + r * DIN;
        float a0 = 0.f, a1 = 0.f, a2 = 0.f, a3 = 0.f;
        #pragma unroll
        for (int d = 0; d < DIN; d += 4) {
            a0 += row[d + 0] * wreg[d + 0];
            a1 += row[d + 1] * wreg[d + 1];
            a2 += row[d + 2] * wreg[d + 2];
            a3 += row[d + 3] * wreg[d + 3];
        }
        atomicAdd(&out[q * DOUT + lane], ((a0 + a1) + (a2 + a3)) * w);
    }
}

// =================================================================================

extern "C" void kernel_launch(void* const* d_in, const int* in_sizes, int n_in,
                              void* d_out, int out_size, void* d_ws, size_t ws_size,
                              hipStream_t stream) {
    const float* W        = (const float*)d_in[0];   // [K0, 64, 64]
    const float* ref      = (const float*)d_in[1];   // [N, 64]
    const int*   e_kernel = (const int*)d_in[2];     // [E]
    const int*   e_ref    = (const int*)d_in[3];     // [E]
    const int*   e_query  = (const int*)d_in[4];     // [E]
    const float* e_weight = (const float*)d_in[6];   // [E]

    const int K0 = in_sizes[0] / (DIN * DOUT);
    const int N  = in_sizes[1] / DIN;
    const int E  = in_sizes[2];
    const int M  = out_size / DOUT;
    const int KD = K0 * 64;
    const int NB = M / QG;           // coarse buckets (128 queries each)

    float* out = (float*)d_out;

    // ---- plan A workspace carve ----
    size_t off = 0;
    auto alloc = [&](size_t bytes, size_t align) {
        off = (off + align - 1) / align * align;
        size_t r = off; off += bytes; return r;
    };
    size_t o_tmp     = alloc((size_t)E * 8, 16);
    size_t o_rec     = alloc((size_t)E * 8, 16);
    size_t o_qstart  = alloc((size_t)(M + 1) * 4, 4);
    size_t o_gbase   = alloc(512 * 4, 4);
    // --- zeroed region (single memset): qcount, gcursor, map ---
    size_t o_qcount  = alloc(512 * 4, 4);
    size_t o_gcursor = alloc(512 * 4, 4);
    size_t o_map     = alloc((size_t)K0 * N, 4);
    size_t zero_end  = off;
    // -----------------------------------------------------------
    size_t o_wt      = alloc((size_t)K0 * 4096 * 2, 16);
    size_t o_T       = alloc((size_t)N * KD * 2, 16);
    size_t needA = off;

    bool planA_ok = (ws_size >= needA) && (M % QG == 0) && (NB >= 1) && (NB <= 512) &&
                    (N % 256 == 0) && (N <= 65536) && (K0 <= 32);

    if (planA_ok) {
        char* ws = (char*)d_ws;
        uint2* tmp           = (uint2*)(ws + o_tmp);
        uint2* rec           = (uint2*)(ws + o_rec);
        int*  qstart         = (int*)(ws + o_qstart);
        int*  gbase          = (int*)(ws + o_gbase);
        int*  qcount         = (int*)(ws + o_qcount);
        int*  gcursor        = (int*)(ws + o_gcursor);
        unsigned char* map   = (unsigned char*)(ws + o_map);
        unsigned short* Wt   = (unsigned short*)(ws + o_wt);
        unsigned short* T    = (unsigned short*)(ws + o_T);

        const int HB   = 512;                       // hist blocks
        const int CWB  = (K0 * 4096 + 255) / 256;   // conv_w blocks
        const int SCB  = (E + 8191) / 8192;         // scatter blocks
        const int NA2  = N / 256;                   // phaseA 16-wave n-blocks
        const int K1   = (K0 < 12) ? K0 : 12;       // unmapped k's (ride scatter)
        const int NS1  = (K1 + KCH - 1) / KCH;
        const int NS2  = (K0 - K1 + KCH - 1) / KCH;

        hipMemsetAsync(ws + o_qcount, 0, zero_end - o_qcount, stream);

        pre_kernel<<<HB + CWB, 256, 0, stream>>>(W, Wt, K0 * 4096,
                                                 e_query, E, qcount, HB);

        fused_scat_kernel<<<SCB + NA2 * NS1, 1024, 0, stream>>>(
            ref, Wt, T, K0, N, SCB, NA2, K1,
            e_query, e_ref, e_kernel, e_weight, E,
            qcount, gbase, gcursor, qstart, M, tmp, map);

        fused_p2_kernel<<<NB + NA2 * NS2, 1024, 0, stream>>>(
            ref, Wt, map, T, K0, N, NB, NA2, K1,
            tmp, gbase, qcount, rec, qstart);

        phaseB_kernel<<<M / 4, 256, 0, stream>>>(T, rec, qstart, out, N);
    } else {
        hipMemsetAsync(out, 0, (size_t)out_size * sizeof(float), stream);
        size_t needB = (size_t)(96 + E) * sizeof(int);
        if (ws_size >= needB) {
            int* ws_i   = (int*)d_ws;
            int* counts = ws_i;
            int* start  = ws_i + 32;
            int* cursor = ws_i + 64;
            int* sorted = ws_i + 96;
            hipMemsetAsync(counts, 0, 96 * sizeof(int), stream);
            hist_kernel<<<512, 256, 0, stream>>>(e_kernel, E, counts);
            scan_kernel<<<1, 64, 0, stream>>>(counts, K0, start, cursor);
            scatter_kernel<<<(E + 255) / 256, 256, 0, stream>>>(e_kernel, E, cursor, sorted);
            dim3 grid(64, K0);
            mp_bucket_kernel<<<grid, 256, 0, stream>>>(W, ref, e_ref, e_query, e_weight,
                                                       sorted, start, counts, out);
        }
    }
}